// Round 7
// baseline (400.433 us; speedup 1.0000x reference)
//
#include <hip/hip_runtime.h>
#include <stdint.h>

// Problem constants (from reference setup_inputs)
#define B_DIM   16384
#define IN_DIM  2048
#define OUT_DIM 2048
#define BN_EPS  1e-5f

typedef int    i32x4 __attribute__((ext_vector_type(4)));
typedef unsigned short u16x4 __attribute__((ext_vector_type(4)));

// ---------- helpers ----------

__device__ __forceinline__ unsigned short f2bf_rne(float f) {
    unsigned u = __builtin_bit_cast(unsigned, f);
    return (unsigned short)((u + 0x7fffu + ((u >> 16) & 1u)) >> 16);
}
__device__ __forceinline__ float bf2f(unsigned short h) {
    unsigned u = ((unsigned)h) << 16;
    return __builtin_bit_cast(float, u);
}

// async global->LDS, 16B per lane. LDS dst = wave-uniform base + lane*16.
__device__ __forceinline__ void gl_lds16(const void* g, void* l) {
    __builtin_amdgcn_global_load_lds(
        (const __attribute__((address_space(1))) unsigned int*)g,
        (__attribute__((address_space(3))) unsigned int*)l,
        16, 0, 0);
}

__device__ __forceinline__ int pack4(float a, float b, float c, float d, float inv) {
    int q0 = (int)rintf(a * inv) & 255;
    int q1 = (int)rintf(b * inv) & 255;
    int q2 = (int)rintf(c * inv) & 255;
    int q3 = (int)rintf(d * inv) & 255;
    return q0 | (q1 << 8) | (q2 << 16) | (q3 << 24);
}

// ---------- kernel 1: x fp32 -> i8 with per-row scale ----------
__global__ __launch_bounds__(256) void quantize_x_kernel(
        const float4* __restrict__ x4, int* __restrict__ xq,
        float* __restrict__ scales) {
    __shared__ float wmax[4];
    const int row = blockIdx.x;
    const int t = threadIdx.x;
    const float4* xr = x4 + (size_t)row * 512;
    float4 a = xr[t];          // 16B coalesced
    float4 b = xr[t + 256];
    float m = fmaxf(fmaxf(fabsf(a.x), fabsf(a.y)), fmaxf(fabsf(a.z), fabsf(a.w)));
    m = fmaxf(m, fmaxf(fmaxf(fabsf(b.x), fabsf(b.y)), fmaxf(fabsf(b.z), fabsf(b.w))));
#pragma unroll
    for (int off = 32; off >= 1; off >>= 1) m = fmaxf(m, __shfl_xor(m, off));
    if ((t & 63) == 0) wmax[t >> 6] = m;
    __syncthreads();
    m = fmaxf(fmaxf(wmax[0], wmax[1]), fmaxf(wmax[2], wmax[3]));
    m = fmaxf(m, 1e-20f);                 // guard all-zero row
    const float inv = 127.0f / m;
    if (t == 0) scales[row] = m * (1.0f / 127.0f);
    int* xo = xq + (size_t)row * 512;
    xo[t]       = pack4(a.x, a.y, a.z, a.w, inv);   // 4B coalesced
    xo[t + 256] = pack4(b.x, b.y, b.z, b.w, inv);
}

// ---------- kernel 2: w fp32 -> sign i8 (+1/-1); also zero stat accums ----------
__global__ __launch_bounds__(256) void convert_w_kernel(
        const float4* __restrict__ w, int* __restrict__ wq,
        float4* __restrict__ stats /* colsum[2048]+colsumsq[2048] */) {
    int id = blockIdx.x * 256 + threadIdx.x;       // exact: 4096 blocks
    if (id < 1024) stats[id] = make_float4(0.f, 0.f, 0.f, 0.f);
    float4 a = w[id];
    int b0 = (a.x < 0.f) ? 0xFF : 0x01;
    int b1 = (a.y < 0.f) ? 0xFF : 0x01;
    int b2 = (a.z < 0.f) ? 0xFF : 0x01;
    int b3 = (a.w < 0.f) ? 0xFF : 0x01;
    wq[id] = b0 | (b1 << 8) | (b2 << 16) | (b3 << 24);
}

// ---------- kernel 3: i8 GEMM (NT) 128x128 tile, A->regs, B->LDS, 3 blk/CU ----
// Round-7 theory (from r4/r6 ablations + cycle model): all prior configs sat at
// 2 waves/SIMD with LDS-port traffic >= the ~85 B/cyc ds_read_b128 ceiling ->
// ~45% of cycles fully stalled regardless of schedule. Fixes, combined:
//  - A fragments load DIRECTLY global->reg (the i8 A-frag layout == row-major
//    global layout: 16 contiguous B per lane = one global_load_dwordx4).
//    A leaves LDS entirely: no A staging writes, no A ds_reads, no A barrier.
//    Pipelined one kk-step ahead (avX/avY), latency hidden under MFMA.
//  - B (4 MB total) staged to LDS (16 KB/tile, proven XOR swizzle), 2-barrier
//    counted-vmcnt cadence. LDS traffic/tile = 48 KB per 4.2 MOP -> 73 B/cyc
//    at full MFMA rate (under the port ceiling; r3 was 137 -> over).
//  - 256 thr (4 waves 2Mx2N, wave 64x64), acc[4][4]=64 regs, total ~140 regs,
//    LDS 32 KB -> __launch_bounds__(256,3): 3 blocks/CU = 12 waves/CU.
//    Independent blocks + per-wave A-slack = the stall-hiding we lacked.
//  - XCD map: xcd=b&7 owns bn pair {2x,2x+1} -> 512 KB B-slice stays L2-hot
//    forever; A streams via L3 (32 MB, fully L3-resident).
__global__ __launch_bounds__(256, 3) void gemm_bn_kernel(
        const char* __restrict__ A, const char* __restrict__ Bw,
        const float* __restrict__ scales,
        unsigned short* __restrict__ Yb,
        float* __restrict__ colsum, float* __restrict__ colsumsq) {
    __shared__ __align__(16) char smem[2 * 16384];   // B dbuf only, 32 KiB

    const int tid  = threadIdx.x;
    const int wave = tid >> 6;
    const int lane = tid & 63;
    const int wm = wave >> 1;         // 0..1 -> 64-row band of M
    const int wn = wave & 1;          // 0..1 -> 64-col band of N
    const int lr = lane & 15;
    const int lq = lane >> 4;

    // per-XCD bn-pair map (grid 2048 = 128 bm x 16 bn, bijective):
    const int b   = blockIdx.x;
    const int xcd = b & 7;
    const int l   = b >> 3;                    // 0..255
    const int bn  = (xcd * 2 + (l & 1)) * 128;
    const int bm  = (l >> 1) * 128;

    // ---- A: per-lane fragment bases (global->reg path) ----
    // frag (i,kk,t): row = bm + wm*64 + i*16 + lr, bytes [t*128+kk*64+lq*16, +16)
    const char* gA0 = A + (size_t)(bm + wm * 64 + lr) * IN_DIM + lq * 16;
    const char* gA1 = gA0 + 1 * 16 * IN_DIM;
    const char* gA2 = gA0 + 2 * 16 * IN_DIM;
    const char* gA3 = gA0 + 3 * 16 * IN_DIM;

    // ---- B staging (gl_lds): sweep = 32 rows x 128 B = 4 KB = 256 thr x 16B.
    // thread row = tid>>3, chunk = tid&7; src chunk = chunk ^ (row&7).
    const int swz16 = (((tid & 7) ^ ((tid >> 3) & 7)) << 4);
    const char* gB = Bw + (size_t)(bn + (tid >> 3)) * IN_DIM + swz16;
    const int ldst = tid << 4;

    // ---- B ds-read: row = wn*64 + j*16 + lr (x128B), slot = (kk*4+lq)^(lr&7)
    const int bRd = (wn * 64 + lr) * 128;
    const int sl0 = ((lq    ) ^ (lr & 7)) << 4;
    const int sl1 = ((lq + 4) ^ (lr & 7)) << 4;

    i32x4 acc[4][4];
#pragma unroll
    for (int i = 0; i < 4; ++i)
#pragma unroll
        for (int j = 0; j < 4; ++j) {
            i32x4 z = {0, 0, 0, 0};
            acc[i][j] = z;
        }

#define VM_WAIT(N) asm volatile("s_waitcnt vmcnt(" #N ")" ::: "memory")
#define BAR()      __builtin_amdgcn_s_barrier()
#define STAGEB(buf_, koff_) do {                                    \
    char* d = smem + (buf_) * 16384;                                \
    gl_lds16(gB + (koff_)          , d + 0 * 4096 + ldst);          \
    gl_lds16(gB + (koff_) +  65536 , d + 1 * 4096 + ldst);          \
    gl_lds16(gB + (koff_) + 131072 , d + 2 * 4096 + ldst);          \
    gl_lds16(gB + (koff_) + 196608 , d + 3 * 4096 + ldst);          \
} while (0)

    i32x4 avX[4], avY[4];

    // prologue: A(0,kk0) -> avX; B tiles 0,1 -> bufs 0,1; leave B(1) in flight
    avX[0] = *(const i32x4*)(gA0);
    avX[1] = *(const i32x4*)(gA1);
    avX[2] = *(const i32x4*)(gA2);
    avX[3] = *(const i32x4*)(gA3);
    STAGEB(0, 0);
    STAGEB(1, 128);
    VM_WAIT(4);        // drain avX + B(0); B(1)'s 4 stay in flight
    BAR();

    const int NT = IN_DIM / 128;    // 16 K-tiles
#pragma unroll
    for (int t = 0; t < NT; ++t) {
        const char* Bb = smem + (t & 1) * 16384;
        // ---- kk = 0: compute avX, prefetch avY = A(t, kk1) ----
        avY[0] = *(const i32x4*)(gA0 + t * 128 + 64);
        avY[1] = *(const i32x4*)(gA1 + t * 128 + 64);
        avY[2] = *(const i32x4*)(gA2 + t * 128 + 64);
        avY[3] = *(const i32x4*)(gA3 + t * 128 + 64);
        {
            i32x4 bv[4];
#pragma unroll
            for (int j = 0; j < 4; ++j)
                bv[j] = *(const i32x4*)(Bb + bRd + j * 2048 + sl0);
            __builtin_amdgcn_s_setprio(1);
#pragma unroll
            for (int i = 0; i < 4; ++i)
#pragma unroll
                for (int j = 0; j < 4; ++j)
                    acc[i][j] = __builtin_amdgcn_mfma_i32_16x16x64_i8(
                        avX[i], bv[j], acc[i][j], 0, 0, 0);
            __builtin_amdgcn_s_setprio(0);
        }
        // ---- kk = 1: compute avY, prefetch avX = A(t+1, kk0) ----
        if (t + 1 < NT) {
            avX[0] = *(const i32x4*)(gA0 + (t + 1) * 128);
            avX[1] = *(const i32x4*)(gA1 + (t + 1) * 128);
            avX[2] = *(const i32x4*)(gA2 + (t + 1) * 128);
            avX[3] = *(const i32x4*)(gA3 + (t + 1) * 128);
        }
        {
            i32x4 bv[4];
#pragma unroll
            for (int j = 0; j < 4; ++j)
                bv[j] = *(const i32x4*)(Bb + bRd + j * 2048 + sl1);
            __builtin_amdgcn_s_setprio(1);
#pragma unroll
            for (int i = 0; i < 4; ++i)
#pragma unroll
                for (int j = 0; j < 4; ++j)
                    acc[i][j] = __builtin_amdgcn_mfma_i32_16x16x64_i8(
                        avY[i], bv[j], acc[i][j], 0, 0, 0);
            __builtin_amdgcn_s_setprio(0);
        }
        // ---- staging & sync (B only) ----
        if (t + 2 < NT) {
            BAR();                          // all waves done reading buf (t&1)
            STAGEB(t & 1, (t + 2) * 128);   // overwrite with B(t+2)
            VM_WAIT(4);                     // drain B(t+1)+A prefetch; B(t+2) in flight
            BAR();                          // B(t+1) visible
        } else if (t + 1 < NT) {
            BAR();
            VM_WAIT(0);                     // drain B(t+1) + A(t+1)
            BAR();
        }
    }

#undef STAGEB
#undef VM_WAIT
#undef BAR

    // epilogue: y = scales[m] * acc (C/D layout: col = lr, row = lq*4 + r)
    float colS[4], colQ[4];
#pragma unroll
    for (int j = 0; j < 4; ++j) { colS[j] = 0.f; colQ[j] = 0.f; }

#pragma unroll
    for (int i = 0; i < 4; ++i) {
        const int row0 = bm + wm * 64 + i * 16 + lq * 4;
        float sc[4];
#pragma unroll
        for (int r = 0; r < 4; ++r) sc[r] = scales[row0 + r];
#pragma unroll
        for (int r = 0; r < 4; ++r) {
            size_t base = (size_t)(row0 + r) * OUT_DIM + bn + wn * 64 + lr;
#pragma unroll
            for (int j = 0; j < 4; ++j) {
                float v = (float)acc[i][j][r] * sc[r];
                Yb[base + j * 16] = f2bf_rne(v);
                colS[j] += v;
                colQ[j] += v * v;
            }
        }
    }

    // per-column partial sum / sumsq -> atomics (combine 4 quads = 4 row groups)
#pragma unroll
    for (int j = 0; j < 4; ++j) {
        float s = colS[j], q = colQ[j];
        s += __shfl_xor(s, 16); s += __shfl_xor(s, 32);
        q += __shfl_xor(q, 16); q += __shfl_xor(q, 32);
        if (lq == 0) {
            int col = bn + wn * 64 + j * 16 + lr;
            atomicAdd(&colsum[col], s);
            atomicAdd(&colsumsq[col], q);
        }
    }
}

// ---------- kernel 4: finalize BN params ----------
__global__ __launch_bounds__(256) void finalize_kernel(
        const float* __restrict__ colsum, const float* __restrict__ colsumsq,
        const float* __restrict__ gamma, const float* __restrict__ beta,
        float* __restrict__ scale, float* __restrict__ bias) {
    int n = blockIdx.x * 256 + threadIdx.x;
    if (n < OUT_DIM) {
        const float inv = 1.f / (float)B_DIM;
        float mean = colsum[n] * inv;
        float var  = colsumsq[n] * inv - mean * mean;
        float sc   = gamma[n] * rsqrtf(var + BN_EPS);
        scale[n] = sc;
        bias[n]  = beta[n] - mean * sc;
    }
}

// ---------- kernel 5: bf16 Y -> affine+ReLU -> fp32 out. 8 elems/thread ----------
__global__ __launch_bounds__(256) void bn_relu_bf16_kernel(
        const u16x4* __restrict__ yb, float4* __restrict__ out,
        const float4* __restrict__ scale4, const float4* __restrict__ bias4) {
    int base = blockIdx.x * 512 + threadIdx.x;   // block covers 512 f4-groups
#pragma unroll
    for (int p = 0; p < 2; ++p) {
        int id = base + p * 256;                 // coalesced both passes
        int c4 = id & (OUT_DIM / 4 - 1);         // column group (2048%4==0)
        u16x4 h = yb[id];                        // 8B coalesced read
        float4 s = scale4[c4];
        float4 bb = bias4[c4];
        float4 v;
        v.x = fmaxf(fmaf(bf2f(h[0]), s.x, bb.x), 0.f);
        v.y = fmaxf(fmaf(bf2f(h[1]), s.y, bb.y), 0.f);
        v.z = fmaxf(fmaf(bf2f(h[2]), s.z, bb.z), 0.f);
        v.w = fmaxf(fmaf(bf2f(h[3]), s.w, bb.w), 0.f);
        out[id] = v;                             // 16B coalesced write
    }
}

// ---------- launch ----------
extern "C" void kernel_launch(void* const* d_in, const int* in_sizes, int n_in,
                              void* d_out, int out_size, void* d_ws, size_t ws_size,
                              hipStream_t stream) {
    const float* x     = (const float*)d_in[0];   // [16384, 2048]
    const float* w     = (const float*)d_in[1];   // [2048, 2048]
    const float* gamma = (const float*)d_in[2];   // [2048]
    const float* beta  = (const float*)d_in[3];   // [2048]
    float* out = (float*)d_out;                   // [16384, 2048]

    char* ws = (char*)d_ws;
    // ws layout: xq 32MB | wq 4MB | yb 64MB | stats 32KB | scales 64KB
    const size_t XQ_OFF = 0;
    const size_t WQ_OFF = XQ_OFF + (size_t)B_DIM * IN_DIM;          // 33,554,432
    const size_t YB_OFF = WQ_OFF + (size_t)OUT_DIM * IN_DIM;        // 37,748,736
    const size_t ST_OFF = YB_OFF + (size_t)B_DIM * OUT_DIM * 2;     // 104,857,600
    const size_t SC_OFF = ST_OFF + 8192 * 4;                        // 104,890,368

    char* xq = ws + XQ_OFF;
    char* wq = ws + WQ_OFF;
    unsigned short* yb = (unsigned short*)(ws + YB_OFF);
    float* colsum   = (float*)(ws + ST_OFF);
    float* colsumsq = colsum + 2048;
    float* scale    = colsum + 4096;
    float* bias     = colsum + 6144;
    float* scales   = (float*)(ws + SC_OFF);      // per-row x scales [16384]

    quantize_x_kernel<<<B_DIM, 256, 0, stream>>>(
        (const float4*)x, (int*)xq, scales);
    convert_w_kernel<<<4096, 256, 0, stream>>>(
        (const float4*)w, (int*)wq, (float4*)colsum);
    gemm_bn_kernel<<<2048, 256, 0, stream>>>(
        xq, wq, scales, yb, colsum, colsumsq);
    finalize_kernel<<<8, 256, 0, stream>>>(
        colsum, colsumsq, gamma, beta, scale, bias);
    bn_relu_bf16_kernel<<<16384, 256, 0, stream>>>(
        (const u16x4*)yb, (float4*)out, (const float4*)scale,
        (const float4*)bias);
}

// Round 9
// 329.855 us; speedup vs baseline: 1.2140x; 1.2140x over previous
//
#include <hip/hip_runtime.h>
#include <stdint.h>

// Problem constants (from reference setup_inputs)
#define B_DIM   16384
#define IN_DIM  2048
#define OUT_DIM 2048
#define BN_EPS  1e-5f

typedef int    i32x4  __attribute__((ext_vector_type(4)));
typedef int    i32x16 __attribute__((ext_vector_type(16)));
typedef unsigned short u16x4 __attribute__((ext_vector_type(4)));

// ---------- helpers ----------

__device__ __forceinline__ unsigned short f2bf_rne(float f) {
    unsigned u = __builtin_bit_cast(unsigned, f);
    return (unsigned short)((u + 0x7fffu + ((u >> 16) & 1u)) >> 16);
}
__device__ __forceinline__ float bf2f(unsigned short h) {
    unsigned u = ((unsigned)h) << 16;
    return __builtin_bit_cast(float, u);
}

// async global->LDS, 16B per lane. LDS dst = wave-uniform base + lane*16.
__device__ __forceinline__ void gl_lds16(const void* g, void* l) {
    __builtin_amdgcn_global_load_lds(
        (const __attribute__((address_space(1))) unsigned int*)g,
        (__attribute__((address_space(3))) unsigned int*)l,
        16, 0, 0);
}

__device__ __forceinline__ int pack4(float a, float b, float c, float d, float inv) {
    int q0 = (int)rintf(a * inv) & 255;
    int q1 = (int)rintf(b * inv) & 255;
    int q2 = (int)rintf(c * inv) & 255;
    int q3 = (int)rintf(d * inv) & 255;
    return q0 | (q1 << 8) | (q2 << 16) | (q3 << 24);
}

// ---------- kernel 1: x fp32 -> i8 with per-row scale ----------
__global__ __launch_bounds__(256) void quantize_x_kernel(
        const float4* __restrict__ x4, int* __restrict__ xq,
        float* __restrict__ scales) {
    __shared__ float wmax[4];
    const int row = blockIdx.x;
    const int t = threadIdx.x;
    const float4* xr = x4 + (size_t)row * 512;
    float4 a = xr[t];          // 16B coalesced
    float4 b = xr[t + 256];
    float m = fmaxf(fmaxf(fabsf(a.x), fabsf(a.y)), fmaxf(fabsf(a.z), fabsf(a.w)));
    m = fmaxf(m, fmaxf(fmaxf(fabsf(b.x), fabsf(b.y)), fmaxf(fabsf(b.z), fabsf(b.w))));
#pragma unroll
    for (int off = 32; off >= 1; off >>= 1) m = fmaxf(m, __shfl_xor(m, off));
    if ((t & 63) == 0) wmax[t >> 6] = m;
    __syncthreads();
    m = fmaxf(fmaxf(wmax[0], wmax[1]), fmaxf(wmax[2], wmax[3]));
    m = fmaxf(m, 1e-20f);                 // guard all-zero row
    const float inv = 127.0f / m;
    if (t == 0) scales[row] = m * (1.0f / 127.0f);
    int* xo = xq + (size_t)row * 512;
    xo[t]       = pack4(a.x, a.y, a.z, a.w, inv);   // 4B coalesced
    xo[t + 256] = pack4(b.x, b.y, b.z, b.w, inv);
}

// ---------- kernel 2: w fp32 -> sign i8 (+1/-1); also zero stat accums ----------
__global__ __launch_bounds__(256) void convert_w_kernel(
        const float4* __restrict__ w, int* __restrict__ wq,
        float4* __restrict__ stats /* colsum[2048]+colsumsq[2048] */) {
    int id = blockIdx.x * 256 + threadIdx.x;       // exact: 4096 blocks
    if (id < 1024) stats[id] = make_float4(0.f, 0.f, 0.f, 0.f);
    float4 a = w[id];
    int b0 = (a.x < 0.f) ? 0xFF : 0x01;
    int b1 = (a.y < 0.f) ? 0xFF : 0x01;
    int b2 = (a.z < 0.f) ? 0xFF : 0x01;
    int b3 = (a.w < 0.f) ? 0xFF : 0x01;
    wq[id] = b0 | (b1 << 8) | (b2 << 16) | (b3 << 24);
}

// ---------- kernel 3: i8 GEMM (NT) 256x256, r1 schedule + 32x32x32 MFMA ----------
// Round-8: exact r1 structure (best measured: 78.7us) with the compute recast
// as mfma_i32_32x32x32_i8 (4404 TOPS ubench vs 3944 for 16x16x64 = +12% rate,
// and HALF the MFMA instruction count per OP -> frees issue slots that compete
// with ds_read/staging issue in each window). LDS bytes/layout/staging are
// byte-identical to r1 -> isolates "MFMA issue+rate" as the only variable.
// Fragments: per wave (128x64 tile): A 4 row-frags x 4 k-frags, B 2 col-frags
// x 4 k-frags, 32 MFMA/K-tile. A/B lane layout: row=lane&31, k=(lane>>5)*16
// +[0,16) -> chunk=(kf*2+hi)^(l31&7) under the same XOR swizzle.
// C/D layout (m74/m101, dtype-independent): col=lane&31,
// row=(reg&3)+8*(reg>>2)+4*(lane>>5).
__global__ __launch_bounds__(512, 2) void gemm_bn_kernel(
        const char* __restrict__ A, const char* __restrict__ Bw,
        const float* __restrict__ scales,
        unsigned short* __restrict__ Yb,
        float* __restrict__ colsum, float* __restrict__ colsumsq) {
    __shared__ __align__(16) char smem[131072];  // [2 buf][A 32K | B 32K]

    const int tid  = threadIdx.x;
    const int wave = tid >> 6;
    const int lane = tid & 63;
    const int wm = wave >> 2;         // 0..1 -> 128-row band of M
    const int wn = wave & 3;          // 0..3 -> 64-col band of N
    const int l31 = lane & 31;
    const int hi  = lane >> 5;

    // XCD swizzle (512 blocks, 512%8==0 -> simple bijection)
    const int b  = blockIdx.x;                 // 0..511
    const int lb = (b & 7) * 64 + (b >> 3);
    const int bm = (lb >> 3) * 256;            // 64 M tiles
    const int bn = (lb & 7) * 256;             // 8 N tiles

    // ---- staging addressing (identical to r1) ----
    // sweep = 64 rows x 128B = 8KB = 512 thr x 16B; thread row = tid>>3,
    // chunk = tid&7; source chunk = chunk ^ (row&7) (sweep bases %8==0).
    const int swz16 = (((tid & 7) ^ ((tid >> 3) & 7)) << 4);
    const char* gA = A  + (size_t)(bm + (tid >> 3)) * IN_DIM + swz16;
    const char* gB = Bw + (size_t)(bn + (tid >> 3)) * IN_DIM + swz16;
    const int ldst = tid << 4;

    // ---- ds-read addressing ----
    // A frag (i,kf): row = wm*128 + i*32 + l31 (x128B), chunk = (kf*2+hi)^(l31&7)
    const int sw   = l31 & 7;
    const int aRd  = (wm * 128 + l31) * 128;             // + i*32*128
    const int bRd  = 32768 + (wn * 64 + l31) * 128;      // + j*32*128

    i32x16 acc[4][2];
#pragma unroll
    for (int i = 0; i < 4; ++i)
#pragma unroll
        for (int j = 0; j < 2; ++j)
            acc[i][j] = (i32x16)(0);

#define VM_WAIT(N) asm volatile("s_waitcnt vmcnt(" #N ")" ::: "memory")
#define LGKM0()    asm volatile("s_waitcnt lgkmcnt(0)" ::: "memory")
#define BAR()      __builtin_amdgcn_s_barrier()
#define ACHUNK(kf_) ((((kf_) * 2 + hi) ^ sw) << 4)
#define ARD(Ab_, i_, kf_) (*(const i32x4*)((Ab_) + aRd + (i_) * 4096 + ACHUNK(kf_)))
#define BRD(Ab_, j_, kf_) (*(const i32x4*)((Ab_) + bRd + (j_) * 4096 + ACHUNK(kf_)))

// 8 MFMA cluster: i in {i0,i0+1}, j in {0,1}, kf in {f0,f0+1}
#define MM8(I0) \
    _Pragma("unroll") for (int ii = 0; ii < 2; ++ii) \
    _Pragma("unroll") for (int jj = 0; jj < 2; ++jj) \
    _Pragma("unroll") for (int ff = 0; ff < 2; ++ff) \
        acc[(I0) + ii][jj] = __builtin_amdgcn_mfma_i32_32x32x32_i8( \
            av[ii][ff], bv[jj][ff], acc[(I0) + ii][jj], 0, 0, 0)

    // prologue: stage tile 0 into buffer 0 (order B0-3, A0, A2, A1, A3)
    {
        char* An = smem;
        char* Bn = smem + 32768;
        gl_lds16(gB + 0 * 131072, Bn + 0 * 8192 + ldst);
        gl_lds16(gB + 1 * 131072, Bn + 1 * 8192 + ldst);
        gl_lds16(gB + 2 * 131072, Bn + 2 * 8192 + ldst);
        gl_lds16(gB + 3 * 131072, Bn + 3 * 8192 + ldst);
        gl_lds16(gA + 0 * 131072, An + 0 * 8192 + ldst);
        gl_lds16(gA + 2 * 131072, An + 2 * 8192 + ldst);
        gl_lds16(gA + 1 * 131072, An + 1 * 8192 + ldst);
        gl_lds16(gA + 3 * 131072, An + 3 * 8192 + ldst);
        VM_WAIT(2);                // B0-3,A0,A2 landed; A1,A3 stay in flight
        BAR();
    }

#define GTILE(t_, LAST_) do {                                                  \
    const char* Ab = smem + (((t_) & 1) ? 65536 : 0);                          \
    char* An = smem + (((t_) & 1) ? 0 : 65536);                                \
    char* Bn = An + 32768;                                                     \
    const size_t kn = (size_t)((t_) + 1) * 128;                                \
    i32x4 av[2][2], bv[2][2];                                                  \
    /* phase 0: i={0,1}, kf={0,1} (needs B0-3, A0, A2 of cur) */               \
    _Pragma("unroll") for (int jj = 0; jj < 2; ++jj)                           \
    _Pragma("unroll") for (int ff = 0; ff < 2; ++ff)                           \
        bv[jj][ff] = BRD(Ab, jj, ff);                                          \
    _Pragma("unroll") for (int ii = 0; ii < 2; ++ii)                           \
    _Pragma("unroll") for (int ff = 0; ff < 2; ++ff)                           \
        av[ii][ff] = ARD(Ab, ii, ff);                                          \
    if (!(LAST_)) {                                                            \
        gl_lds16(gB + kn          , Bn + 0 * 8192 + ldst);                     \
        gl_lds16(gB + kn + 131072 , Bn + 1 * 8192 + ldst);                     \
        gl_lds16(gB + kn + 262144 , Bn + 2 * 8192 + ldst);                     \
        gl_lds16(gB + kn + 393216 , Bn + 3 * 8192 + ldst);                     \
    }                                                                          \
    if (LAST_) { VM_WAIT(0); } else { VM_WAIT(4); } /* drain cur A1,A3 */      \
    BAR(); LGKM0();                                                            \
    __builtin_amdgcn_s_setprio(1);                                             \
    MM8(0);                                                                    \
    __builtin_amdgcn_s_setprio(0);                                             \
    BAR();                                                                     \
    /* phase 1: i={2,3}, kf={0,1} (needs A1, A3 of cur; bv reused) */          \
    _Pragma("unroll") for (int ii = 0; ii < 2; ++ii)                           \
    _Pragma("unroll") for (int ff = 0; ff < 2; ++ff)                           \
        av[ii][ff] = ARD(Ab, ii + 2, ff);                                      \
    if (!(LAST_)) {                                                            \
        gl_lds16(gA + kn          , An + 0 * 8192 + ldst);                     \
        gl_lds16(gA + kn + 262144 , An + 2 * 8192 + ldst);                     \
        gl_lds16(gA + kn + 131072 , An + 1 * 8192 + ldst);                     \
        gl_lds16(gA + kn + 393216 , An + 3 * 8192 + ldst);                     \
    }                                                                          \
    BAR(); LGKM0();                                                            \
    __builtin_amdgcn_s_setprio(1);                                             \
    MM8(2);                                                                    \
    __builtin_amdgcn_s_setprio(0);                                             \
    BAR();                                                                     \
    /* phase 2: i={0,1}, kf={2,3} (cur fully resident) */                      \
    _Pragma("unroll") for (int jj = 0; jj < 2; ++jj)                           \
    _Pragma("unroll") for (int ff = 0; ff < 2; ++ff)                           \
        bv[jj][ff] = BRD(Ab, jj, ff + 2);                                      \
    _Pragma("unroll") for (int ii = 0; ii < 2; ++ii)                           \
    _Pragma("unroll") for (int ff = 0; ff < 2; ++ff)                           \
        av[ii][ff] = ARD(Ab, ii, ff + 2);                                      \
    BAR(); LGKM0();                                                            \
    __builtin_amdgcn_s_setprio(1);                                             \
    MM8(0);                                                                    \
    __builtin_amdgcn_s_setprio(0);                                             \
    BAR();                                                                     \
    /* phase 3: i={2,3}, kf={2,3}; drain nxt B0-3,A0,A2 (A1,A3 in flight) */   \
    _Pragma("unroll") for (int ii = 0; ii < 2; ++ii)                           \
    _Pragma("unroll") for (int ff = 0; ff < 2; ++ff)                           \
        av[ii][ff] = ARD(Ab, ii + 2, ff + 2);                                  \
    VM_WAIT(2);                                                                \
    BAR(); LGKM0();                                                            \
    __builtin_amdgcn_s_setprio(1);                                             \
    MM8(2);                                                                    \
    __builtin_amdgcn_s_setprio(0);                                             \
    BAR();                                                                     \
} while (0)

    for (int t = 0; t < 15; ++t) GTILE(t, 0);
    GTILE(15, 1);

#undef GTILE
#undef MM8
#undef ARD
#undef BRD
#undef ACHUNK
#undef VM_WAIT
#undef LGKM0
#undef BAR

    // epilogue: y = scales[m] * acc
    // C/D layout: col = l31, row = (r&3) + 8*(r>>2) + 4*hi
    float colS[2], colQ[2];
#pragma unroll
    for (int j = 0; j < 2; ++j) { colS[j] = 0.f; colQ[j] = 0.f; }

#pragma unroll
    for (int i = 0; i < 4; ++i) {
#pragma unroll
        for (int r = 0; r < 16; ++r) {
            const int row = bm + wm * 128 + i * 32 + (r & 3) + 8 * (r >> 2) + 4 * hi;
            const float sc = scales[row];
            const size_t base = (size_t)row * OUT_DIM + bn + wn * 64 + l31;
#pragma unroll
            for (int j = 0; j < 2; ++j) {
                float v = (float)acc[i][j][r] * sc;
                Yb[base + j * 32] = f2bf_rne(v);
                colS[j] += v;
                colQ[j] += v * v;
            }
        }
    }

    // per-column stats: lanes l and l+32 share a column (rows differ) ->
    // combine across hi halves, then one atomic per column from hi==0.
#pragma unroll
    for (int j = 0; j < 2; ++j) {
        float s = colS[j], q = colQ[j];
        s += __shfl_xor(s, 32);
        q += __shfl_xor(q, 32);
        if (hi == 0) {
            int col = bn + wn * 64 + j * 32 + l31;
            atomicAdd(&colsum[col], s);
            atomicAdd(&colsumsq[col], q);
        }
    }
}

// ---------- kernel 4: finalize BN params ----------
__global__ __launch_bounds__(256) void finalize_kernel(
        const float* __restrict__ colsum, const float* __restrict__ colsumsq,
        const float* __restrict__ gamma, const float* __restrict__ beta,
        float* __restrict__ scale, float* __restrict__ bias) {
    int n = blockIdx.x * 256 + threadIdx.x;
    if (n < OUT_DIM) {
        const float inv = 1.f / (float)B_DIM;
        float mean = colsum[n] * inv;
        float var  = colsumsq[n] * inv - mean * mean;
        float sc   = gamma[n] * rsqrtf(var + BN_EPS);
        scale[n] = sc;
        bias[n]  = beta[n] - mean * sc;
    }
}

// ---------- kernel 5: bf16 Y -> affine+ReLU -> fp32 out. 8 elems/thread ----------
__global__ __launch_bounds__(256) void bn_relu_bf16_kernel(
        const u16x4* __restrict__ yb, float4* __restrict__ out,
        const float4* __restrict__ scale4, const float4* __restrict__ bias4) {
    int base = blockIdx.x * 512 + threadIdx.x;   // block covers 512 f4-groups
#pragma unroll
    for (int p = 0; p < 2; ++p) {
        int id = base + p * 256;                 // coalesced both passes
        int c4 = id & (OUT_DIM / 4 - 1);         // column group (2048%4==0)
        u16x4 h = yb[id];                        // 8B coalesced read
        float4 s = scale4[c4];
        float4 bb = bias4[c4];
        float4 v;
        v.x = fmaxf(fmaf(bf2f(h[0]), s.x, bb.x), 0.f);
        v.y = fmaxf(fmaf(bf2f(h[1]), s.y, bb.y), 0.f);
        v.z = fmaxf(fmaf(bf2f(h[2]), s.z, bb.z), 0.f);
        v.w = fmaxf(fmaf(bf2f(h[3]), s.w, bb.w), 0.f);
        out[id] = v;                             // 16B coalesced write
    }
}

// ---------- launch ----------
extern "C" void kernel_launch(void* const* d_in, const int* in_sizes, int n_in,
                              void* d_out, int out_size, void* d_ws, size_t ws_size,
                              hipStream_t stream) {
    const float* x     = (const float*)d_in[0];   // [16384, 2048]
    const float* w     = (const float*)d_in[1];   // [2048, 2048]
    const float* gamma = (const float*)d_in[2];   // [2048]
    const float* beta  = (const float*)d_in[3];   // [2048]
    float* out = (float*)d_out;                   // [16384, 2048]

    char* ws = (char*)d_ws;
    // ws layout: xq 32MB | wq 4MB | yb 64MB | stats 32KB | scales 64KB
    const size_t XQ_OFF = 0;
    const size_t WQ_OFF = XQ_OFF + (size_t)B_DIM * IN_DIM;          // 33,554,432
    const size_t YB_OFF = WQ_OFF + (size_t)OUT_DIM * IN_DIM;        // 37,748,736
    const size_t ST_OFF = YB_OFF + (size_t)B_DIM * OUT_DIM * 2;     // 104,857,600
    const size_t SC_OFF = ST_OFF + 8192 * 4;                        // 104,890,368

    char* xq = ws + XQ_OFF;
    char* wq = ws + WQ_OFF;
    unsigned short* yb = (unsigned short*)(ws + YB_OFF);
    float* colsum   = (float*)(ws + ST_OFF);
    float* colsumsq = colsum + 2048;
    float* scale    = colsum + 4096;
    float* bias     = colsum + 6144;
    float* scales   = (float*)(ws + SC_OFF);      // per-row x scales [16384]

    quantize_x_kernel<<<B_DIM, 256, 0, stream>>>(
        (const float4*)x, (int*)xq, scales);
    convert_w_kernel<<<4096, 256, 0, stream>>>(
        (const float4*)w, (int*)wq, (float4*)colsum);
    gemm_bn_kernel<<<512, 512, 0, stream>>>(
        xq, wq, scales, yb, colsum, colsumsq);
    finalize_kernel<<<8, 256, 0, stream>>>(
        colsum, colsumsq, gamma, beta, scale, bias);
    bn_relu_bf16_kernel<<<16384, 256, 0, stream>>>(
        (const u16x4*)yb, (float4*)out, (const float4*)scale,
        (const float4*)bias);
}